// Round 13
// baseline (2135.677 us; speedup 1.0000x reference)
//
#include <hip/hip_runtime.h>
#include <hip/hip_bf16.h>
#include <hip/hip_cooperative_groups.h>
#include <math.h>

// EnhancedResGCN forward. N=100000, E=1600000, IN=128, H=64, C=16, L=4.
// Round 13: cooperative mega-kernel per layer (nb-gather | att+conv | agg-gather+
// BN-partials | reduce | post/postFC with grid.sync) -> 25 to 13 dispatches.

#define EPS_BN 1e-5f
#define GS_BLOCKS 2048

namespace cg = cooperative_groups;

static inline int cdiv_i(int a, int b){ return (a + b - 1) / b; }

typedef __attribute__((ext_vector_type(8))) short bf16x8;
typedef __attribute__((ext_vector_type(4))) float f32x4;
typedef __attribute__((ext_vector_type(4))) unsigned short u16x4;

__device__ inline short f2bf(float f){
  unsigned int u = __builtin_bit_cast(unsigned int, f);
  u += 0x7FFFu + ((u >> 16) & 1u);          // round-to-nearest-even
  return (short)(u >> 16);
}
__device__ inline float bf2f(unsigned short u){
  unsigned int x = ((unsigned int)u) << 16;
  return __builtin_bit_cast(float, x);
}

__device__ inline void pack_w_lds(const float* __restrict__ W, short* WP, int K, int N){
  int NF = N >> 4;
  int items = (K >> 5) * NF * 64;
  for (int i = threadIdx.x; i < items; i += 256){
    int c  = i & 15;
    int kg = (i >> 4) & 3;
    int t2 = i >> 6;
    int nf = t2 % NF, kstep = t2 / NF;
    short* d = &WP[((kstep * NF + nf) * 4 + kg) * 128 + c * 8];
#pragma unroll
    for (int j = 0; j < 8; ++j){
      int k = kstep * 32 + kg * 8 + j;
      d[j] = f2bf(W[(size_t)k * N + nf * 16 + c]);
    }
  }
}
__device__ inline bf16x8 wfrag(const short* WP, int NF, int kstep, int nf, int lgrp, int lrow){
  return *reinterpret_cast<const bf16x8*>(&WP[((kstep * NF + nf) * 4 + lgrp) * 128 + lrow * 8]);
}

// ---------------- CSR build ----------------
__global__ void k_cnt2(const int* __restrict__ src, const int* __restrict__ dst,
                       float* __restrict__ outd, int* __restrict__ cnt,
                       int* __restrict__ rank, int E){
  int base = blockIdx.x * (blockDim.x * 4) + threadIdx.x;
#pragma unroll
  for (int j = 0; j < 4; ++j){
    int e = base + j * 256;
    if (e < E){
      atomicAdd(&outd[src[e]], 1.f);
      rank[e] = atomicAdd(&cnt[dst[e]], 1);
    }
  }
}

#define SCAN_B 256
__global__ void k_scan_a(const int* __restrict__ cnt, int* __restrict__ bsum,
                         float* __restrict__ outn, float* __restrict__ innorm,
                         float* __restrict__ invind, int n){
  __shared__ int sm[SCAN_B];
  int i = blockIdx.x * SCAN_B + threadIdx.x;
  int c = (i < n) ? cnt[i] : 0;
  if (i < n){
    float od = fmaxf(outn[i], 1.f);
    float id = fmaxf((float)c, 1.f);
    outn[i]   = rsqrtf(od);
    innorm[i] = rsqrtf(id);
    invind[i] = 1.f / id;
  }
  sm[threadIdx.x] = c;
  __syncthreads();
  for (int s = SCAN_B / 2; s; s >>= 1){
    if (threadIdx.x < s) sm[threadIdx.x] += sm[threadIdx.x + s];
    __syncthreads();
  }
  if (threadIdx.x == 0) bsum[blockIdx.x] = sm[0];
}

__global__ void k_scan_b(int* __restrict__ bsum, int nb, int* __restrict__ rowptr_n, int E){
  __shared__ int sm[512];
  int t = threadIdx.x;
  int orig = (t < nb) ? bsum[t] : 0;
  sm[t] = orig;
  __syncthreads();
  for (int off = 1; off < 512; off <<= 1){
    int v = (t >= off) ? sm[t - off] : 0;
    __syncthreads();
    sm[t] += v;
    __syncthreads();
  }
  if (t < nb) bsum[t] = sm[t] - orig;
  if (t == 0) *rowptr_n = E;
}

__global__ void k_scan_c(const int* __restrict__ cnt, const int* __restrict__ bsum,
                         int* __restrict__ rowptr, int n){
  __shared__ int sm[SCAN_B];
  int i = blockIdx.x * SCAN_B + threadIdx.x;
  int orig = (i < n) ? cnt[i] : 0;
  sm[threadIdx.x] = orig;
  __syncthreads();
  for (int off = 1; off < SCAN_B; off <<= 1){
    int v = (threadIdx.x >= off) ? sm[threadIdx.x - off] : 0;
    __syncthreads();
    sm[threadIdx.x] += v;
    __syncthreads();
  }
  if (i < n) rowptr[i] = sm[threadIdx.x] - orig + bsum[blockIdx.x];
}

__global__ void k_fill2(const int* __restrict__ src, const int* __restrict__ dst,
                        const int* __restrict__ rowptr, const int* __restrict__ rank,
                        int* __restrict__ csr, int E){
  int base = blockIdx.x * (blockDim.x * 4) + threadIdx.x;
#pragma unroll
  for (int j = 0; j < 4; ++j){
    int e = base + j * 256;
    if (e < E) csr[rowptr[dst[e]] + rank[e]] = src[e];
  }
}

// ---------------- fused encoder + layer-0 conv ----------------
__global__ __launch_bounds__(256) void k_enc(
    const float* __restrict__ features,
    const float* __restrict__ W1, const float* __restrict__ b1,
    const float* __restrict__ W2, const float* __restrict__ b2,
    const float* __restrict__ W3, const float* __restrict__ b3,
    const float* __restrict__ W0, const float* __restrict__ outnorm,
    unsigned short* __restrict__ hw_bf, int n)
{
  __shared__ short WP1[8192];
  __shared__ short WP2[2048];
  __shared__ short WP3[4096];
  __shared__ short stA[9216];
  __shared__ short st2[2560];

  const int tid = threadIdx.x, wave = tid >> 6, lane = tid & 63;
  const int lrow = lane & 15, lgrp = lane >> 4;
  const int row0 = blockIdx.x * 64;
  const int arow = row0 + wave * 16 + lrow;
  const bool rok = arow < n;

  pack_w_lds(W1, WP1, 128, 64);
  pack_w_lds(W2, WP2, 64, 32);
  pack_w_lds(W3, WP3, 32, 128);
  __syncthreads();

  {
    f32x4 acc[4] = {};
#pragma unroll
    for (int kstep = 0; kstep < 4; ++kstep){
      bf16x8 a;
      if (rok){
        const float* p = features + (size_t)arow * 128 + kstep * 32 + lgrp * 8;
        float4 v0 = *reinterpret_cast<const float4*>(p);
        float4 v1 = *reinterpret_cast<const float4*>(p + 4);
        a[0]=f2bf(v0.x); a[1]=f2bf(v0.y); a[2]=f2bf(v0.z); a[3]=f2bf(v0.w);
        a[4]=f2bf(v1.x); a[5]=f2bf(v1.y); a[6]=f2bf(v1.z); a[7]=f2bf(v1.w);
      } else {
#pragma unroll
        for (int j = 0; j < 8; ++j) a[j] = 0;
      }
#pragma unroll
      for (int nf = 0; nf < 4; ++nf)
        acc[nf] = __builtin_amdgcn_mfma_f32_16x16x32_bf16(a, wfrag(WP1,4,kstep,nf,lgrp,lrow), acc[nf], 0,0,0);
    }
#pragma unroll
    for (int nf = 0; nf < 4; ++nf){
      float bv = b1[nf * 16 + lrow];
#pragma unroll
      for (int r = 0; r < 4; ++r)
        stA[(wave*16 + lgrp*4 + r) * 72 + nf*16 + lrow] = f2bf(fmaxf(acc[nf][r] + bv, 0.f));
    }
  }
  __syncthreads();

  pack_w_lds(W0, WP1, 128, 64);

  {
    f32x4 acc[2] = {};
#pragma unroll
    for (int kstep = 0; kstep < 2; ++kstep){
      bf16x8 a = *reinterpret_cast<const bf16x8*>(&stA[(wave*16 + lrow) * 72 + kstep*32 + lgrp*8]);
#pragma unroll
      for (int nf = 0; nf < 2; ++nf)
        acc[nf] = __builtin_amdgcn_mfma_f32_16x16x32_bf16(a, wfrag(WP2,2,kstep,nf,lgrp,lrow), acc[nf], 0,0,0);
    }
#pragma unroll
    for (int nf = 0; nf < 2; ++nf){
      float bv = b2[nf * 16 + lrow];
#pragma unroll
      for (int r = 0; r < 4; ++r)
        st2[(wave*16 + lgrp*4 + r) * 40 + nf*16 + lrow] = f2bf(fmaxf(acc[nf][r] + bv, 0.f));
    }
  }
  __syncthreads();

  {
    f32x4 acc[8] = {};
    bf16x8 a = *reinterpret_cast<const bf16x8*>(&st2[(wave*16 + lrow) * 40 + lgrp*8]);
#pragma unroll
    for (int nf = 0; nf < 8; ++nf)
      acc[nf] = __builtin_amdgcn_mfma_f32_16x16x32_bf16(a, wfrag(WP3,8,0,nf,lgrp,lrow), acc[nf], 0,0,0);
    __syncthreads();
#pragma unroll
    for (int nf = 0; nf < 8; ++nf){
      float bv = b3[nf * 16 + lrow];
#pragma unroll
      for (int r = 0; r < 4; ++r)
        stA[(wave*16 + lgrp*4 + r) * 136 + nf*16 + lrow] = f2bf(acc[nf][r] + bv);
    }
  }
  __syncthreads();

  {
    const float rs = rok ? outnorm[arow] : 0.f;
    f32x4 acc[4] = {};
#pragma unroll
    for (int kstep = 0; kstep < 4; ++kstep){
      bf16x8 raw = *reinterpret_cast<const bf16x8*>(&stA[(wave*16 + lrow) * 136 + kstep*32 + lgrp*8]);
      bf16x8 a;
#pragma unroll
      for (int j = 0; j < 8; ++j) a[j] = f2bf(bf2f((unsigned short)raw[j]) * rs);
#pragma unroll
      for (int nf = 0; nf < 4; ++nf)
        acc[nf] = __builtin_amdgcn_mfma_f32_16x16x32_bf16(a, wfrag(WP1,4,kstep,nf,lgrp,lrow), acc[nf], 0,0,0);
    }
#pragma unroll
    for (int nf = 0; nf < 4; ++nf){
#pragma unroll
      for (int r = 0; r < 4; ++r){
        int orow = row0 + wave*16 + lgrp*4 + r;
        if (orow < n) hw_bf[(size_t)orow * 64 + nf*16 + lrow] = (unsigned short)f2bf(acc[nf][r]);
      }
    }
  }
}

// ---------------- layer-0 helpers (standalone path) ----------------
__global__ __launch_bounds__(256) void k_gather_stats(
    const unsigned short* __restrict__ x, const int* __restrict__ rowptr,
    const int* __restrict__ csr, const float* __restrict__ innorm,
    const float* __restrict__ b, float* __restrict__ agg,
    float* __restrict__ p1, float* __restrict__ p2, int n){
  __shared__ float s1[4][64], s2[4][64];
  int g = threadIdx.x >> 6, f = threadIdx.x & 63;
  float bf = b[f];
  float z1 = 0.f, z2 = 0.f;
  for (int node = blockIdx.x * 4 + g; node < n; node += GS_BLOCKS * 4){
    int beg = rowptr[node], end = rowptr[node + 1];
    float a0 = 0.f, a1 = 0.f, a2 = 0.f, a3 = 0.f;
    int e = beg;
    for (; e + 3 < end; e += 4){
      int s0v = csr[e], s1v = csr[e+1], s2v = csr[e+2], s3v = csr[e+3];
      a0 += bf2f(x[(size_t)s0v * 64 + f]);
      a1 += bf2f(x[(size_t)s1v * 64 + f]);
      a2 += bf2f(x[(size_t)s2v * 64 + f]);
      a3 += bf2f(x[(size_t)s3v * 64 + f]);
    }
    for (; e < end; ++e) a0 += bf2f(x[(size_t)csr[e] * 64 + f]);
    float s = (a0 + a1) + (a2 + a3);
    agg[(size_t)node * 64 + f] = s;
    float z = s * innorm[node] + bf;
    z1 += z; z2 += z * z;
  }
  s1[g][f] = z1; s2[g][f] = z2;
  __syncthreads();
  if (threadIdx.x < 64){
    p1[(size_t)blockIdx.x * 64 + f] = s1[0][f] + s1[1][f] + s1[2][f] + s1[3][f];
    p2[(size_t)blockIdx.x * 64 + f] = s2[0][f] + s2[1][f] + s2[2][f] + s2[3][f];
  }
}

__global__ void k_bnred(const float* __restrict__ p1, const float* __restrict__ p2,
                        float* __restrict__ bnsum, float* __restrict__ bnsq){
  __shared__ float sm[256];
  int f = blockIdx.x & 63, stat = blockIdx.x >> 6;
  const float* p = stat ? p2 : p1;
  float a = 0.f;
  for (int i = threadIdx.x; i < GS_BLOCKS; i += 256) a += p[(size_t)i * 64 + f];
  sm[threadIdx.x] = a;
  __syncthreads();
  for (int s = 128; s; s >>= 1){
    if (threadIdx.x < s) sm[threadIdx.x] += sm[threadIdx.x + s];
    __syncthreads();
  }
  if (threadIdx.x == 0) (stat ? bnsq : bnsum)[f] = sm[0];
}

__global__ void k_post(const float* __restrict__ agg, const float* __restrict__ innorm,
                       const float* __restrict__ b, const float* __restrict__ bnsum,
                       const float* __restrict__ bnsq, const float* __restrict__ gamma,
                       const float* __restrict__ beta, float inv_n,
                       const float* __restrict__ hres,
                       float* __restrict__ hout, unsigned short* __restrict__ hbf, int n16){
  int i = blockIdx.x * blockDim.x + threadIdx.x;
  if (i >= n16) return;
  int row = i >> 4, fq = (i & 15) * 4;
  size_t o = (size_t)row * 64 + fq;
  float inn = innorm[row];
  float4 av = *reinterpret_cast<const float4*>(&agg[o]);
  float4 rv = hres ? *reinterpret_cast<const float4*>(&hres[o]) : (float4){0.f,0.f,0.f,0.f};
  float r[4]; float aa[4] = {av.x, av.y, av.z, av.w}; float rr[4] = {rv.x, rv.y, rv.z, rv.w};
#pragma unroll
  for (int j = 0; j < 4; ++j){
    int f = fq + j;
    float mu  = bnsum[f] * inv_n;
    float var = bnsq[f] * inv_n - mu * mu;
    float sc  = gamma[f] * rsqrtf(var + EPS_BN);
    float sh  = beta[f] - mu * sc;
    float z = aa[j] * inn + b[f];
    z = z * sc + sh + rr[j];
    r[j] = fmaxf(z, 0.f);
  }
  *reinterpret_cast<float4*>(&hout[o]) = (float4){r[0], r[1], r[2], r[3]};
  u16x4 hb;
#pragma unroll
  for (int j = 0; j < 4; ++j) hb[j] = (unsigned short)f2bf(r[j]);
  *reinterpret_cast<u16x4*>(&hbf[o]) = hb;
}

// ---------------- cooperative per-layer mega-kernel (layers 1..3) ----------------
struct KL {
  float* h; unsigned short* h_bf; unsigned short* nb_bf; unsigned short* hw_bf;
  float* agg; float* p1; float* p2; float* bnsum; float* bnsq;
  const float* invind; const float* innorm; const float* outnorm;
  const int* rowptr; const int* csr;
  const float* W1; const float* b1; const float* W2; const float* b2;
  const float* Wi; const float* bi; const float* gamma; const float* beta;
  const float* fcW; const float* fcb; float* outp;
  float inv_n; int n; int last;
};

__global__ __launch_bounds__(256, 4) void k_layer(KL A){
  cg::grid_group grid = cg::this_grid();
  __shared__ __align__(16) short WP[4096];      // 8 KB weight pack (serial reuse)
  __shared__ __align__(16) short ht[64 * 72];   // 9.2 KB tile buffer
  __shared__ float sred[256];

  const int tid = threadIdx.x, wave = tid >> 6, lane = tid & 63;
  const int lrow = lane & 15, lgrp = lane >> 4;
  const int G = gridDim.x;
  const int n = A.n;
  const int nt = (n + 63) >> 6;

  // ---- phase A: nb_bf = gather(h_bf), unroll-8 ----
  {
    int g = wave, f = lane;
    for (int node = blockIdx.x * 4 + g; node < n; node += G * 4){
      int beg = A.rowptr[node], end = A.rowptr[node + 1];
      float a0=0.f,a1=0.f,a2=0.f,a3=0.f,a4=0.f,a5=0.f,a6=0.f,a7=0.f;
      int e = beg;
      for (; e + 7 < end; e += 8){
        a0 += bf2f(A.h_bf[(size_t)A.csr[e  ] * 64 + f]);
        a1 += bf2f(A.h_bf[(size_t)A.csr[e+1] * 64 + f]);
        a2 += bf2f(A.h_bf[(size_t)A.csr[e+2] * 64 + f]);
        a3 += bf2f(A.h_bf[(size_t)A.csr[e+3] * 64 + f]);
        a4 += bf2f(A.h_bf[(size_t)A.csr[e+4] * 64 + f]);
        a5 += bf2f(A.h_bf[(size_t)A.csr[e+5] * 64 + f]);
        a6 += bf2f(A.h_bf[(size_t)A.csr[e+6] * 64 + f]);
        a7 += bf2f(A.h_bf[(size_t)A.csr[e+7] * 64 + f]);
      }
      for (; e < end; ++e) a0 += bf2f(A.h_bf[(size_t)A.csr[e] * 64 + f]);
      float s = ((a0+a1)+(a2+a3)) + ((a4+a5)+(a6+a7));
      A.nb_bf[(size_t)node * 64 + f] = (unsigned short)f2bf(s);
    }
  }
  grid.sync();

  // ---- phase B: attention + conv per 64-row tile ----
  for (int t = blockIdx.x; t < nt; t += G){
    const int row0 = t * 64;
    const int arow = row0 + wave * 16 + lrow;
    const bool rok = arow < n;

    __syncthreads();
    pack_w_lds(A.W1, WP, 64, 64);             // W1 h-half
    __syncthreads();

    f32x4 acc[4];
#pragma unroll
    for (int nf = 0; nf < 4; ++nf) acc[nf] = (f32x4){0.f,0.f,0.f,0.f};
#pragma unroll
    for (int kstep = 0; kstep < 2; ++kstep){
      bf16x8 a;
      if (rok){
        const float* p = A.h + (size_t)arow * 64 + kstep * 32 + lgrp * 8;
        float4 v0 = *reinterpret_cast<const float4*>(p);
        float4 v1 = *reinterpret_cast<const float4*>(p + 4);
        a[0]=f2bf(v0.x); a[1]=f2bf(v0.y); a[2]=f2bf(v0.z); a[3]=f2bf(v0.w);
        a[4]=f2bf(v1.x); a[5]=f2bf(v1.y); a[6]=f2bf(v1.z); a[7]=f2bf(v1.w);
      } else {
#pragma unroll
        for (int j = 0; j < 8; ++j) a[j] = 0;
      }
#pragma unroll
      for (int nf = 0; nf < 4; ++nf)
        acc[nf] = __builtin_amdgcn_mfma_f32_16x16x32_bf16(a, wfrag(WP,4,kstep,nf,lgrp,lrow), acc[nf], 0,0,0);
    }
    __syncthreads();
    pack_w_lds(A.W1 + 64 * 64, WP, 64, 64);   // W1 nb-half
    __syncthreads();
    const float iv = rok ? A.invind[arow] : 0.f;
#pragma unroll
    for (int kstep = 0; kstep < 2; ++kstep){
      bf16x8 a;
      if (rok){
        bf16x8 raw = *reinterpret_cast<const bf16x8*>(
            A.nb_bf + (size_t)arow * 64 + kstep * 32 + lgrp * 8);
#pragma unroll
        for (int j = 0; j < 8; ++j) a[j] = f2bf(bf2f((unsigned short)raw[j]) * iv);
      } else {
#pragma unroll
        for (int j = 0; j < 8; ++j) a[j] = 0;
      }
#pragma unroll
      for (int nf = 0; nf < 4; ++nf)
        acc[nf] = __builtin_amdgcn_mfma_f32_16x16x32_bf16(a, wfrag(WP,4,kstep,nf,lgrp,lrow), acc[nf], 0,0,0);
    }

    // gate + h update; stash h_new tile
    const float w2l[4] = {A.W2[lrow], A.W2[16 + lrow], A.W2[32 + lrow], A.W2[48 + lrow]};
    const float b2v = A.b2[0];
#pragma unroll
    for (int r = 0; r < 4; ++r){
      int orow = row0 + wave*16 + lgrp*4 + r;
      float p = 0.f;
#pragma unroll
      for (int nf = 0; nf < 4; ++nf)
        p += fmaxf(acc[nf][r] + A.b1[nf * 16 + lrow], 0.f) * w2l[nf];
      p += __shfl_xor(p, 1); p += __shfl_xor(p, 2);
      p += __shfl_xor(p, 4); p += __shfl_xor(p, 8);
      short h0 = 0, h1v = 0, h2v = 0, h3v = 0;
      if (orow < n){
        float a = 1.f / (1.f + expf(-(p + b2v)));
        float ivr = A.invind[orow];
        const unsigned short* np = A.nb_bf + (size_t)orow * 64 + lrow * 4;
        float4 hv = *reinterpret_cast<float4*>(&A.h[(size_t)orow * 64 + lrow * 4]);
        hv.x += a * bf2f(np[0]) * ivr; hv.y += a * bf2f(np[1]) * ivr;
        hv.z += a * bf2f(np[2]) * ivr; hv.w += a * bf2f(np[3]) * ivr;
        *reinterpret_cast<float4*>(&A.h[(size_t)orow * 64 + lrow * 4]) = hv;
        h0 = f2bf(hv.x); h1v = f2bf(hv.y); h2v = f2bf(hv.z); h3v = f2bf(hv.w);
      }
      short* d = &ht[(wave*16 + lgrp*4 + r) * 72 + lrow * 4];
      d[0] = h0; d[1] = h1v; d[2] = h2v; d[3] = h3v;
    }
    __syncthreads();
    pack_w_lds(A.Wi, WP, 64, 64);             // conv weight
    __syncthreads();

    const float rs = rok ? A.outnorm[arow] : 0.f;
    f32x4 cacc[4];
#pragma unroll
    for (int nf = 0; nf < 4; ++nf) cacc[nf] = (f32x4){0.f,0.f,0.f,0.f};
#pragma unroll
    for (int kstep = 0; kstep < 2; ++kstep){
      bf16x8 raw = *reinterpret_cast<const bf16x8*>(&ht[(wave*16 + lrow) * 72 + kstep*32 + lgrp*8]);
      bf16x8 a;
#pragma unroll
      for (int j = 0; j < 8; ++j) a[j] = f2bf(bf2f((unsigned short)raw[j]) * rs);
#pragma unroll
      for (int nf = 0; nf < 4; ++nf)
        cacc[nf] = __builtin_amdgcn_mfma_f32_16x16x32_bf16(a, wfrag(WP,4,kstep,nf,lgrp,lrow), cacc[nf], 0,0,0);
    }
#pragma unroll
    for (int nf = 0; nf < 4; ++nf){
#pragma unroll
      for (int r = 0; r < 4; ++r){
        int orow = row0 + wave*16 + lgrp*4 + r;
        if (orow < n) A.hw_bf[(size_t)orow * 64 + nf*16 + lrow] = (unsigned short)f2bf(cacc[nf][r]);
      }
    }
  }
  grid.sync();

  // ---- phase C: agg gather + BN partials (unroll-8) ----
  {
    int g = wave, f = lane;
    float bf = A.bi[f];
    float z1 = 0.f, z2 = 0.f;
    for (int node = blockIdx.x * 4 + g; node < n; node += G * 4){
      int beg = A.rowptr[node], end = A.rowptr[node + 1];
      float a0=0.f,a1=0.f,a2=0.f,a3=0.f,a4=0.f,a5=0.f,a6=0.f,a7=0.f;
      int e = beg;
      for (; e + 7 < end; e += 8){
        a0 += bf2f(A.hw_bf[(size_t)A.csr[e  ] * 64 + f]);
        a1 += bf2f(A.hw_bf[(size_t)A.csr[e+1] * 64 + f]);
        a2 += bf2f(A.hw_bf[(size_t)A.csr[e+2] * 64 + f]);
        a3 += bf2f(A.hw_bf[(size_t)A.csr[e+3] * 64 + f]);
        a4 += bf2f(A.hw_bf[(size_t)A.csr[e+4] * 64 + f]);
        a5 += bf2f(A.hw_bf[(size_t)A.csr[e+5] * 64 + f]);
        a6 += bf2f(A.hw_bf[(size_t)A.csr[e+6] * 64 + f]);
        a7 += bf2f(A.hw_bf[(size_t)A.csr[e+7] * 64 + f]);
      }
      for (; e < end; ++e) a0 += bf2f(A.hw_bf[(size_t)A.csr[e] * 64 + f]);
      float s = ((a0+a1)+(a2+a3)) + ((a4+a5)+(a6+a7));
      A.agg[(size_t)node * 64 + f] = s;
      float z = s * A.innorm[node] + bf;
      z1 += z; z2 += z * z;
    }
    float* s1 = (float*)ht;          // reuse ht as [4][64]+[4][64] float scratch
    float* s2 = s1 + 256;
    __syncthreads();                 // all ht (phase B) reads long done; re-purpose
    s1[g * 64 + f] = z1; s2[g * 64 + f] = z2;
    __syncthreads();
    if (tid < 64){
      A.p1[(size_t)blockIdx.x * 64 + tid] = s1[tid] + s1[64+tid] + s1[128+tid] + s1[192+tid];
      A.p2[(size_t)blockIdx.x * 64 + tid] = s2[tid] + s2[64+tid] + s2[128+tid] + s2[192+tid];
    }
  }
  grid.sync();

  // ---- phase D: reduce partials -> bnsum/bnsq (blocks 0..127) ----
  if (blockIdx.x < 128){
    int f = blockIdx.x & 63, stat = blockIdx.x >> 6;
    const float* p = stat ? A.p2 : A.p1;
    float a = 0.f;
    for (int i = tid; i < G; i += 256) a += p[(size_t)i * 64 + f];
    sred[tid] = a;
    __syncthreads();
    for (int s = 128; s; s >>= 1){
      if (tid < s) sred[tid] += sred[tid + s];
      __syncthreads();
    }
    if (tid == 0) (stat ? A.bnsq : A.bnsum)[f] = sred[0];
  }
  grid.sync();

  // ---- phase E ----
  if (!A.last){
    int n16 = n * 16;
    for (int i = blockIdx.x * 256 + tid; i < n16; i += G * 256){
      int row = i >> 4, fq = (i & 15) * 4;
      size_t o = (size_t)row * 64 + fq;
      float inn = A.innorm[row];
      float4 av = *reinterpret_cast<const float4*>(&A.agg[o]);
      float4 rv = *reinterpret_cast<const float4*>(&A.h[o]);
      float r[4]; float aa[4] = {av.x, av.y, av.z, av.w}; float rr[4] = {rv.x, rv.y, rv.z, rv.w};
#pragma unroll
      for (int j = 0; j < 4; ++j){
        int f = fq + j;
        float mu  = A.bnsum[f] * A.inv_n;
        float var = A.bnsq[f] * A.inv_n - mu * mu;
        float sc  = A.gamma[f] * rsqrtf(var + EPS_BN);
        float sh  = A.beta[f] - mu * sc;
        float z = aa[j] * inn + A.bi[f];
        z = z * sc + sh + rr[j];
        r[j] = fmaxf(z, 0.f);
      }
      *reinterpret_cast<float4*>(&A.h[o]) = (float4){r[0], r[1], r[2], r[3]};
      u16x4 hb;
#pragma unroll
      for (int j = 0; j < 4; ++j) hb[j] = (unsigned short)f2bf(r[j]);
      *reinterpret_cast<u16x4*>(&A.h_bf[o]) = hb;
    }
  } else {
    for (int t = blockIdx.x; t < nt; t += G){
      const int row0 = t * 64;
      __syncthreads();
      pack_w_lds(A.fcW, WP, 64, 16);
      // BN + residual + relu into ht (bf16)
#pragma unroll
      for (int j = 0; j < 16; ++j){
        int idx = j * 256 + tid;
        int row = idx >> 6, f = idx & 63;
        int grow = row0 + row;
        float r = 0.f;
        if (grow < n){
          float mu  = A.bnsum[f] * A.inv_n;
          float var = A.bnsq[f] * A.inv_n - mu * mu;
          float sc  = A.gamma[f] * rsqrtf(var + EPS_BN);
          float sh  = A.beta[f] - mu * sc;
          float z = A.agg[(size_t)grow * 64 + f] * A.innorm[grow] + A.bi[f];
          z = z * sc + sh + A.h[(size_t)grow * 64 + f];
          r = fmaxf(z, 0.f);
        }
        ht[row * 72 + f] = f2bf(r);
      }
      __syncthreads();
      f32x4 acc = (f32x4){0.f,0.f,0.f,0.f};
#pragma unroll
      for (int kstep = 0; kstep < 2; ++kstep){
        bf16x8 a = *reinterpret_cast<const bf16x8*>(&ht[(wave*16 + lrow) * 72 + kstep*32 + lgrp*8]);
        acc = __builtin_amdgcn_mfma_f32_16x16x32_bf16(a, wfrag(WP,1,kstep,0,lgrp,lrow), acc, 0,0,0);
      }
      float bv = A.fcb[lrow];
#pragma unroll
      for (int r = 0; r < 4; ++r){
        int orow = row0 + wave*16 + lgrp*4 + r;
        if (orow < n) A.outp[(size_t)orow * 16 + lrow] = acc[r] + bv;
      }
      __syncthreads();
    }
  }
}

extern "C" void kernel_launch(void* const* d_in, const int* in_sizes, int n_in,
                              void* d_out, int out_size, void* d_ws, size_t ws_size,
                              hipStream_t stream) {
  const float* features = (const float*)d_in[0];
  const int*   src      = (const int*)d_in[1];
  const int*   dst      = (const int*)d_in[2];
  const float* encW1 = (const float*)d_in[3];  const float* encb1 = (const float*)d_in[4];
  const float* encW2 = (const float*)d_in[5];  const float* encb2 = (const float*)d_in[6];
  const float* encW3 = (const float*)d_in[7];  const float* encb3 = (const float*)d_in[8];
  const float* attW1 = (const float*)d_in[9];  const float* attb1 = (const float*)d_in[10];
  const float* attW2 = (const float*)d_in[11]; const float* attb2 = (const float*)d_in[12];
  const float* W0    = (const float*)d_in[13]; const float* b0    = (const float*)d_in[14];
  const float* Wrest = (const float*)d_in[15]; const float* brest = (const float*)d_in[16];
  const float* gamma = (const float*)d_in[17]; const float* beta  = (const float*)d_in[18];
  const float* fcW   = (const float*)d_in[19]; const float* fcb   = (const float*)d_in[20];
  float* out = (float*)d_out;

  const int n = in_sizes[0] / 128;   // 100000
  const int E = in_sizes[1];         // 1600000

  float* ws      = (float*)d_ws;
  float* agg     = ws;
  unsigned short* h_bf = (unsigned short*)(ws + (size_t)n * 64);
  float* p1      = ws + (size_t)n * 96;
  float* p2      = p1 + (size_t)GS_BLOCKS * 64;
  float* hbuf    = ws + (size_t)n * 128;
  float* nbhw    = hbuf + (size_t)n * 64;
  float* outnorm = nbhw + (size_t)n * 64;
  int*   cnt     = (int*)(outnorm + n);
  float* innorm  = (float*)(cnt + n);
  float* invind  = innorm + n;
  float* bnsum   = invind + n;
  float* bnsq    = bnsum + 256;
  int* rowptr = (int*)(bnsq + 256);
  int* csr    = rowptr + n + 1;
  int* bsum   = csr + E;
  int* rank = (int*)nbhw;
  unsigned short* nb_bf = (unsigned short*)nbhw;
  unsigned short* hw_bf = (unsigned short*)(nbhw + (size_t)n * 32);

  const int nt = cdiv_i(n, 64);
  const int nb = cdiv_i(n, SCAN_B);
  const float inv_n = 1.f / (float)n;

  // cooperative grid size: co-resident capacity (256 CUs)
  int bpc = 0;
  hipOccupancyMaxActiveBlocksPerMultiprocessor(&bpc, (const void*)k_layer, 256, 0);
  if (bpc < 1) bpc = 1;
  int G = bpc * 256;
  if (G > 1024) G = 1024;

  // ---- CSR build ----
  hipMemsetAsync(outnorm, 0, 2 * (size_t)n * sizeof(float), stream);
  k_cnt2<<<cdiv_i(E, 1024), 256, 0, stream>>>(src, dst, outnorm, cnt, rank, E);
  k_scan_a<<<nb, SCAN_B, 0, stream>>>(cnt, bsum, outnorm, innorm, invind, n);
  k_scan_b<<<1, 512, 0, stream>>>(bsum, nb, rowptr + n, E);
  k_scan_c<<<nb, SCAN_B, 0, stream>>>(cnt, bsum, rowptr, n);
  k_fill2<<<cdiv_i(E, 1024), 256, 0, stream>>>(src, dst, rowptr, rank, csr, E);

  // ---- layer 0 (standalone chain) ----
  k_enc<<<nt, 256, 0, stream>>>(features, encW1, encb1, encW2, encb2, encW3, encb3,
                                W0, outnorm, hw_bf, n);
  k_gather_stats<<<GS_BLOCKS, 256, 0, stream>>>(hw_bf, rowptr, csr, innorm, b0, agg, p1, p2, n);
  k_bnred<<<128, 256, 0, stream>>>(p1, p2, bnsum, bnsq);
  k_post<<<cdiv_i(n * 16, 256), 256, 0, stream>>>(agg, innorm, b0, bnsum, bnsq, gamma, beta, inv_n,
                                                  nullptr, hbuf, h_bf, n * 16);

  // ---- layers 1..3 (cooperative mega-kernels) ----
  for (int i = 1; i < 4; ++i){
    KL a;
    a.h = hbuf; a.h_bf = h_bf; a.nb_bf = nb_bf; a.hw_bf = hw_bf;
    a.agg = agg; a.p1 = p1; a.p2 = p2;
    a.bnsum = bnsum + i * 64; a.bnsq = bnsq + i * 64;
    a.invind = invind; a.innorm = innorm; a.outnorm = outnorm;
    a.rowptr = rowptr; a.csr = csr;
    a.W1 = attW1; a.b1 = attb1; a.W2 = attW2; a.b2 = attb2;
    a.Wi = Wrest + (size_t)(i - 1) * 64 * 64;
    a.bi = brest + (size_t)(i - 1) * 64;
    a.gamma = gamma + i * 64; a.beta = beta + i * 64;
    a.fcW = fcW; a.fcb = fcb; a.outp = out;
    a.inv_n = inv_n; a.n = n; a.last = (i == 3) ? 1 : 0;
    void* kargs[] = { (void*)&a };
    hipLaunchCooperativeKernel((const void*)k_layer, dim3(G), dim3(256), kargs, 0, stream);
  }
}

// Round 15
// 800.561 us; speedup vs baseline: 2.6677x; 2.6677x over previous
//
#include <hip/hip_runtime.h>
#include <hip/hip_bf16.h>
#include <math.h>

// EnhancedResGCN forward. N=100000, E=1600000, IN=128, H=64, C=16, L=4.
// Round 14 (resubmit; infra failure): Round-12 structure + unroll-8 ILP in
// gather kernels. Cooperative experiment reverted (788->2136 regression).

#define EPS_BN 1e-5f
#define GS_BLOCKS 2048

static inline int cdiv_i(int a, int b){ return (a + b - 1) / b; }

typedef __attribute__((ext_vector_type(8))) short bf16x8;
typedef __attribute__((ext_vector_type(4))) float f32x4;
typedef __attribute__((ext_vector_type(4))) unsigned short u16x4;

__device__ inline short f2bf(float f){
  unsigned int u = __builtin_bit_cast(unsigned int, f);
  u += 0x7FFFu + ((u >> 16) & 1u);          // round-to-nearest-even
  return (short)(u >> 16);
}
__device__ inline float bf2f(unsigned short u){
  unsigned int x = ((unsigned int)u) << 16;
  return __builtin_bit_cast(float, x);
}

__device__ inline void pack_w_lds(const float* __restrict__ W, short* WP, int K, int N){
  int NF = N >> 4;
  int items = (K >> 5) * NF * 64;
  for (int i = threadIdx.x; i < items; i += 256){
    int c  = i & 15;
    int kg = (i >> 4) & 3;
    int t2 = i >> 6;
    int nf = t2 % NF, kstep = t2 / NF;
    short* d = &WP[((kstep * NF + nf) * 4 + kg) * 128 + c * 8];
#pragma unroll
    for (int j = 0; j < 8; ++j){
      int k = kstep * 32 + kg * 8 + j;
      d[j] = f2bf(W[(size_t)k * N + nf * 16 + c]);
    }
  }
}
__device__ inline bf16x8 wfrag(const short* WP, int NF, int kstep, int nf, int lgrp, int lrow){
  return *reinterpret_cast<const bf16x8*>(&WP[((kstep * NF + nf) * 4 + lgrp) * 128 + lrow * 8]);
}

// ---------------- degree count + per-edge rank, 4 edges/thread ----------------
__global__ void k_cnt2(const int* __restrict__ src, const int* __restrict__ dst,
                       float* __restrict__ outd, int* __restrict__ cnt,
                       int* __restrict__ rank, int E){
  int base = blockIdx.x * (blockDim.x * 4) + threadIdx.x;
#pragma unroll
  for (int j = 0; j < 4; ++j){
    int e = base + j * 256;
    if (e < E){
      atomicAdd(&outd[src[e]], 1.f);
      rank[e] = atomicAdd(&cnt[dst[e]], 1);
    }
  }
}

// ---------------- scan stage A + degree norms (merged) ----------------
#define SCAN_B 256
__global__ void k_scan_a(const int* __restrict__ cnt, int* __restrict__ bsum,
                         float* __restrict__ outn, float* __restrict__ innorm,
                         float* __restrict__ invind, int n){
  __shared__ int sm[SCAN_B];
  int i = blockIdx.x * SCAN_B + threadIdx.x;
  int c = (i < n) ? cnt[i] : 0;
  if (i < n){
    float od = fmaxf(outn[i], 1.f);        // outn holds outd here
    float id = fmaxf((float)c, 1.f);
    outn[i]   = rsqrtf(od);
    innorm[i] = rsqrtf(id);
    invind[i] = 1.f / id;
  }
  sm[threadIdx.x] = c;
  __syncthreads();
  for (int s = SCAN_B / 2; s; s >>= 1){
    if (threadIdx.x < s) sm[threadIdx.x] += sm[threadIdx.x + s];
    __syncthreads();
  }
  if (threadIdx.x == 0) bsum[blockIdx.x] = sm[0];
}

__global__ void k_scan_b(int* __restrict__ bsum, int nb, int* __restrict__ rowptr_n, int E){
  __shared__ int sm[512];
  int t = threadIdx.x;
  int orig = (t < nb) ? bsum[t] : 0;
  sm[t] = orig;
  __syncthreads();
  for (int off = 1; off < 512; off <<= 1){
    int v = (t >= off) ? sm[t - off] : 0;
    __syncthreads();
    sm[t] += v;
    __syncthreads();
  }
  if (t < nb) bsum[t] = sm[t] - orig;
  if (t == 0) *rowptr_n = E;
}

__global__ void k_scan_c(const int* __restrict__ cnt, const int* __restrict__ bsum,
                         int* __restrict__ rowptr, int n){
  __shared__ int sm[SCAN_B];
  int i = blockIdx.x * SCAN_B + threadIdx.x;
  int orig = (i < n) ? cnt[i] : 0;
  sm[threadIdx.x] = orig;
  __syncthreads();
  for (int off = 1; off < SCAN_B; off <<= 1){
    int v = (threadIdx.x >= off) ? sm[threadIdx.x - off] : 0;
    __syncthreads();
    sm[threadIdx.x] += v;
    __syncthreads();
  }
  if (i < n) rowptr[i] = sm[threadIdx.x] - orig + bsum[blockIdx.x];
}

__global__ void k_fill2(const int* __restrict__ src, const int* __restrict__ dst,
                        const int* __restrict__ rowptr, const int* __restrict__ rank,
                        int* __restrict__ csr, int E){
  int base = blockIdx.x * (blockDim.x * 4) + threadIdx.x;
#pragma unroll
  for (int j = 0; j < 4; ++j){
    int e = base + j * 256;
    if (e < E) csr[rowptr[dst[e]] + rank[e]] = src[e];
  }
}

// ---------------- fused encoder + layer-0 conv: 4 chained MFMA stages ----------------
__global__ __launch_bounds__(256) void k_enc(
    const float* __restrict__ features,
    const float* __restrict__ W1, const float* __restrict__ b1,
    const float* __restrict__ W2, const float* __restrict__ b2,
    const float* __restrict__ W3, const float* __restrict__ b3,
    const float* __restrict__ W0, const float* __restrict__ outnorm,
    unsigned short* __restrict__ hw_bf, int n)
{
  __shared__ short WP1[8192];
  __shared__ short WP2[2048];
  __shared__ short WP3[4096];
  __shared__ short stA[9216];
  __shared__ short st2[2560];

  const int tid = threadIdx.x, wave = tid >> 6, lane = tid & 63;
  const int lrow = lane & 15, lgrp = lane >> 4;
  const int row0 = blockIdx.x * 64;
  const int arow = row0 + wave * 16 + lrow;
  const bool rok = arow < n;

  pack_w_lds(W1, WP1, 128, 64);
  pack_w_lds(W2, WP2, 64, 32);
  pack_w_lds(W3, WP3, 32, 128);
  __syncthreads();

  {
    f32x4 acc[4] = {};
#pragma unroll
    for (int kstep = 0; kstep < 4; ++kstep){
      bf16x8 a;
      if (rok){
        const float* p = features + (size_t)arow * 128 + kstep * 32 + lgrp * 8;
        float4 v0 = *reinterpret_cast<const float4*>(p);
        float4 v1 = *reinterpret_cast<const float4*>(p + 4);
        a[0]=f2bf(v0.x); a[1]=f2bf(v0.y); a[2]=f2bf(v0.z); a[3]=f2bf(v0.w);
        a[4]=f2bf(v1.x); a[5]=f2bf(v1.y); a[6]=f2bf(v1.z); a[7]=f2bf(v1.w);
      } else {
#pragma unroll
        for (int j = 0; j < 8; ++j) a[j] = 0;
      }
#pragma unroll
      for (int nf = 0; nf < 4; ++nf)
        acc[nf] = __builtin_amdgcn_mfma_f32_16x16x32_bf16(a, wfrag(WP1,4,kstep,nf,lgrp,lrow), acc[nf], 0,0,0);
    }
#pragma unroll
    for (int nf = 0; nf < 4; ++nf){
      float bv = b1[nf * 16 + lrow];
#pragma unroll
      for (int r = 0; r < 4; ++r)
        stA[(wave*16 + lgrp*4 + r) * 72 + nf*16 + lrow] = f2bf(fmaxf(acc[nf][r] + bv, 0.f));
    }
  }
  __syncthreads();

  pack_w_lds(W0, WP1, 128, 64);

  {
    f32x4 acc[2] = {};
#pragma unroll
    for (int kstep = 0; kstep < 2; ++kstep){
      bf16x8 a = *reinterpret_cast<const bf16x8*>(&stA[(wave*16 + lrow) * 72 + kstep*32 + lgrp*8]);
#pragma unroll
      for (int nf = 0; nf < 2; ++nf)
        acc[nf] = __builtin_amdgcn_mfma_f32_16x16x32_bf16(a, wfrag(WP2,2,kstep,nf,lgrp,lrow), acc[nf], 0,0,0);
    }
#pragma unroll
    for (int nf = 0; nf < 2; ++nf){
      float bv = b2[nf * 16 + lrow];
#pragma unroll
      for (int r = 0; r < 4; ++r)
        st2[(wave*16 + lgrp*4 + r) * 40 + nf*16 + lrow] = f2bf(fmaxf(acc[nf][r] + bv, 0.f));
    }
  }
  __syncthreads();

  {
    f32x4 acc[8] = {};
    bf16x8 a = *reinterpret_cast<const bf16x8*>(&st2[(wave*16 + lrow) * 40 + lgrp*8]);
#pragma unroll
    for (int nf = 0; nf < 8; ++nf)
      acc[nf] = __builtin_amdgcn_mfma_f32_16x16x32_bf16(a, wfrag(WP3,8,0,nf,lgrp,lrow), acc[nf], 0,0,0);
    __syncthreads();
#pragma unroll
    for (int nf = 0; nf < 8; ++nf){
      float bv = b3[nf * 16 + lrow];
#pragma unroll
      for (int r = 0; r < 4; ++r)
        stA[(wave*16 + lgrp*4 + r) * 136 + nf*16 + lrow] = f2bf(acc[nf][r] + bv);
    }
  }
  __syncthreads();

  {
    const float rs = rok ? outnorm[arow] : 0.f;
    f32x4 acc[4] = {};
#pragma unroll
    for (int kstep = 0; kstep < 4; ++kstep){
      bf16x8 raw = *reinterpret_cast<const bf16x8*>(&stA[(wave*16 + lrow) * 136 + kstep*32 + lgrp*8]);
      bf16x8 a;
#pragma unroll
      for (int j = 0; j < 8; ++j) a[j] = f2bf(bf2f((unsigned short)raw[j]) * rs);
#pragma unroll
      for (int nf = 0; nf < 4; ++nf)
        acc[nf] = __builtin_amdgcn_mfma_f32_16x16x32_bf16(a, wfrag(WP1,4,kstep,nf,lgrp,lrow), acc[nf], 0,0,0);
    }
#pragma unroll
    for (int nf = 0; nf < 4; ++nf){
#pragma unroll
      for (int r = 0; r < 4; ++r){
        int orow = row0 + wave*16 + lgrp*4 + r;
        if (orow < n) hw_bf[(size_t)orow * 64 + nf*16 + lrow] = (unsigned short)f2bf(acc[nf][r]);
      }
    }
  }
}

// ---------------- fused attention + conv GEMM ----------------
__global__ __launch_bounds__(256) void k_attconv(
    float* __restrict__ h, const unsigned short* __restrict__ nb_bf,
    const float* __restrict__ invind, const float* __restrict__ outnorm,
    const float* __restrict__ W1, const float* __restrict__ b1,
    const float* __restrict__ W2, const float* __restrict__ b2,
    const float* __restrict__ Wi, unsigned short* __restrict__ hw_bf, int n)
{
  __shared__ short WPA[8192];
  __shared__ short WPC[4096];
  __shared__ short ht[64 * 72];

  const int tid = threadIdx.x, wave = tid >> 6, lane = tid & 63;
  const int lrow = lane & 15, lgrp = lane >> 4;
  const int row0 = blockIdx.x * 64;
  const int arow = row0 + wave * 16 + lrow;
  const bool rok = arow < n;

  pack_w_lds(W1, WPA, 128, 64);
  pack_w_lds(Wi, WPC, 64, 64);
  __syncthreads();

  const float iv = rok ? invind[arow] : 0.f;
  f32x4 acc[4];
#pragma unroll
  for (int nf = 0; nf < 4; ++nf) acc[nf] = (f32x4){0.f,0.f,0.f,0.f};

#pragma unroll
  for (int kstep = 0; kstep < 4; ++kstep){
    bf16x8 a;
    if (rok){
      if (kstep < 2){
        const float* p = h + (size_t)arow * 64 + kstep * 32 + lgrp * 8;
        float4 v0 = *reinterpret_cast<const float4*>(p);
        float4 v1 = *reinterpret_cast<const float4*>(p + 4);
        a[0]=f2bf(v0.x); a[1]=f2bf(v0.y); a[2]=f2bf(v0.z); a[3]=f2bf(v0.w);
        a[4]=f2bf(v1.x); a[5]=f2bf(v1.y); a[6]=f2bf(v1.z); a[7]=f2bf(v1.w);
      } else {
        const unsigned short* p = nb_bf + (size_t)arow * 64 + (kstep & 1) * 32 + lgrp * 8;
        bf16x8 raw = *reinterpret_cast<const bf16x8*>(p);
#pragma unroll
        for (int j = 0; j < 8; ++j) a[j] = f2bf(bf2f((unsigned short)raw[j]) * iv);
      }
    } else {
#pragma unroll
      for (int j = 0; j < 8; ++j) a[j] = 0;
    }
#pragma unroll
    for (int nf = 0; nf < 4; ++nf)
      acc[nf] = __builtin_amdgcn_mfma_f32_16x16x32_bf16(a, wfrag(WPA,4,kstep,nf,lgrp,lrow), acc[nf], 0,0,0);
  }

  const float w2l[4] = {W2[lrow], W2[16 + lrow], W2[32 + lrow], W2[48 + lrow]};
  const float b2v = b2[0];
#pragma unroll
  for (int r = 0; r < 4; ++r){
    int orow = row0 + wave*16 + lgrp*4 + r;
    float p = 0.f;
#pragma unroll
    for (int nf = 0; nf < 4; ++nf)
      p += fmaxf(acc[nf][r] + b1[nf * 16 + lrow], 0.f) * w2l[nf];
    p += __shfl_xor(p, 1); p += __shfl_xor(p, 2);
    p += __shfl_xor(p, 4); p += __shfl_xor(p, 8);
    short h0 = 0, h1v = 0, h2v = 0, h3v = 0;
    if (orow < n){
      float a = 1.f / (1.f + expf(-(p + b2v)));
      float ivr = invind[orow];
      const unsigned short* np = nb_bf + (size_t)orow * 64 + lrow * 4;
      float4 hv = *reinterpret_cast<float4*>(&h[(size_t)orow * 64 + lrow * 4]);
      hv.x += a * bf2f(np[0]) * ivr; hv.y += a * bf2f(np[1]) * ivr;
      hv.z += a * bf2f(np[2]) * ivr; hv.w += a * bf2f(np[3]) * ivr;
      *reinterpret_cast<float4*>(&h[(size_t)orow * 64 + lrow * 4]) = hv;
      h0 = f2bf(hv.x); h1v = f2bf(hv.y); h2v = f2bf(hv.z); h3v = f2bf(hv.w);
    }
    short* d = &ht[(wave*16 + lgrp*4 + r) * 72 + lrow * 4];
    d[0] = h0; d[1] = h1v; d[2] = h2v; d[3] = h3v;
  }
  __syncthreads();

  {
    const float rs = rok ? outnorm[arow] : 0.f;
    f32x4 cacc[4];
#pragma unroll
    for (int nf = 0; nf < 4; ++nf) cacc[nf] = (f32x4){0.f,0.f,0.f,0.f};
#pragma unroll
    for (int kstep = 0; kstep < 2; ++kstep){
      bf16x8 raw = *reinterpret_cast<const bf16x8*>(&ht[(wave*16 + lrow) * 72 + kstep*32 + lgrp*8]);
      bf16x8 a;
#pragma unroll
      for (int j = 0; j < 8; ++j) a[j] = f2bf(bf2f((unsigned short)raw[j]) * rs);
#pragma unroll
      for (int nf = 0; nf < 4; ++nf)
        cacc[nf] = __builtin_amdgcn_mfma_f32_16x16x32_bf16(a, wfrag(WPC,4,kstep,nf,lgrp,lrow), cacc[nf], 0,0,0);
    }
#pragma unroll
    for (int nf = 0; nf < 4; ++nf){
#pragma unroll
      for (int r = 0; r < 4; ++r){
        int orow = row0 + wave*16 + lgrp*4 + r;
        if (orow < n) hw_bf[(size_t)orow * 64 + nf*16 + lrow] = (unsigned short)f2bf(cacc[nf][r]);
      }
    }
  }
}

// ---------------- nb gather (bf16 in, bf16 out), wave per node, unroll-8 ----------------
__global__ void k_gather_nb(const unsigned short* __restrict__ x,
                            const int* __restrict__ rowptr, const int* __restrict__ csr,
                            unsigned short* __restrict__ outv, int n){
  int node = blockIdx.x * 4 + (threadIdx.x >> 6);
  int f = threadIdx.x & 63;
  if (node >= n) return;
  int beg = rowptr[node], end = rowptr[node + 1];
  float a0=0.f,a1=0.f,a2=0.f,a3=0.f,a4=0.f,a5=0.f,a6=0.f,a7=0.f;
  int e = beg;
  for (; e + 7 < end; e += 8){
    a0 += bf2f(x[(size_t)csr[e  ] * 64 + f]);
    a1 += bf2f(x[(size_t)csr[e+1] * 64 + f]);
    a2 += bf2f(x[(size_t)csr[e+2] * 64 + f]);
    a3 += bf2f(x[(size_t)csr[e+3] * 64 + f]);
    a4 += bf2f(x[(size_t)csr[e+4] * 64 + f]);
    a5 += bf2f(x[(size_t)csr[e+5] * 64 + f]);
    a6 += bf2f(x[(size_t)csr[e+6] * 64 + f]);
    a7 += bf2f(x[(size_t)csr[e+7] * 64 + f]);
  }
  for (; e < end; ++e) a0 += bf2f(x[(size_t)csr[e] * 64 + f]);
  outv[(size_t)node * 64 + f] = (unsigned short)f2bf(((a0+a1)+(a2+a3)) + ((a4+a5)+(a6+a7)));
}

// ---------------- agg gather + fused BN partial stats (grid-stride), unroll-8 ----------------
__global__ __launch_bounds__(256) void k_gather_stats(
    const unsigned short* __restrict__ x, const int* __restrict__ rowptr,
    const int* __restrict__ csr, const float* __restrict__ innorm,
    const float* __restrict__ b, float* __restrict__ agg,
    float* __restrict__ p1, float* __restrict__ p2, int n){
  __shared__ float s1[4][64], s2[4][64];
  int g = threadIdx.x >> 6, f = threadIdx.x & 63;
  float bf = b[f];
  float z1 = 0.f, z2 = 0.f;
  for (int node = blockIdx.x * 4 + g; node < n; node += GS_BLOCKS * 4){
    int beg = rowptr[node], end = rowptr[node + 1];
    float a0=0.f,a1=0.f,a2=0.f,a3=0.f,a4=0.f,a5=0.f,a6=0.f,a7=0.f;
    int e = beg;
    for (; e + 7 < end; e += 8){
      a0 += bf2f(x[(size_t)csr[e  ] * 64 + f]);
      a1 += bf2f(x[(size_t)csr[e+1] * 64 + f]);
      a2 += bf2f(x[(size_t)csr[e+2] * 64 + f]);
      a3 += bf2f(x[(size_t)csr[e+3] * 64 + f]);
      a4 += bf2f(x[(size_t)csr[e+4] * 64 + f]);
      a5 += bf2f(x[(size_t)csr[e+5] * 64 + f]);
      a6 += bf2f(x[(size_t)csr[e+6] * 64 + f]);
      a7 += bf2f(x[(size_t)csr[e+7] * 64 + f]);
    }
    for (; e < end; ++e) a0 += bf2f(x[(size_t)csr[e] * 64 + f]);
    float s = ((a0+a1)+(a2+a3)) + ((a4+a5)+(a6+a7));
    agg[(size_t)node * 64 + f] = s;
    float z = s * innorm[node] + bf;
    z1 += z; z2 += z * z;
  }
  s1[g][f] = z1; s2[g][f] = z2;
  __syncthreads();
  if (threadIdx.x < 64){
    p1[(size_t)blockIdx.x * 64 + f] = s1[0][f] + s1[1][f] + s1[2][f] + s1[3][f];
    p2[(size_t)blockIdx.x * 64 + f] = s2[0][f] + s2[1][f] + s2[2][f] + s2[3][f];
  }
}

// ---------------- reduce partials -> bnsum/bnsq ----------------
__global__ void k_bnred(const float* __restrict__ p1, const float* __restrict__ p2,
                        float* __restrict__ bnsum, float* __restrict__ bnsq){
  __shared__ float sm[256];
  int f = blockIdx.x & 63, stat = blockIdx.x >> 6;
  const float* p = stat ? p2 : p1;
  float a = 0.f;
  for (int i = threadIdx.x; i < GS_BLOCKS; i += 256) a += p[(size_t)i * 64 + f];
  sm[threadIdx.x] = a;
  __syncthreads();
  for (int s = 128; s; s >>= 1){
    if (threadIdx.x < s) sm[threadIdx.x] += sm[threadIdx.x + s];
    __syncthreads();
  }
  if (threadIdx.x == 0) (stat ? bnsq : bnsum)[f] = sm[0];
}

// ---------------- epilogue (layers 0-2): float4 ----------------
__global__ void k_post(const float* __restrict__ agg, const float* __restrict__ innorm,
                       const float* __restrict__ b, const float* __restrict__ bnsum,
                       const float* __restrict__ bnsq, const float* __restrict__ gamma,
                       const float* __restrict__ beta, float inv_n,
                       const float* __restrict__ hres,
                       float* __restrict__ hout, unsigned short* __restrict__ hbf, int n16){
  int i = blockIdx.x * blockDim.x + threadIdx.x;
  if (i >= n16) return;
  int row = i >> 4, fq = (i & 15) * 4;
  size_t o = (size_t)row * 64 + fq;
  float inn = innorm[row];
  float4 av = *reinterpret_cast<const float4*>(&agg[o]);
  float4 rv = hres ? *reinterpret_cast<const float4*>(&hres[o]) : (float4){0.f,0.f,0.f,0.f};
  float r[4]; float aa[4] = {av.x, av.y, av.z, av.w}; float rr[4] = {rv.x, rv.y, rv.z, rv.w};
#pragma unroll
  for (int j = 0; j < 4; ++j){
    int f = fq + j;
    float mu  = bnsum[f] * inv_n;
    float var = bnsq[f] * inv_n - mu * mu;
    float sc  = gamma[f] * rsqrtf(var + EPS_BN);
    float sh  = beta[f] - mu * sc;
    float z = aa[j] * inn + b[f];
    z = z * sc + sh + rr[j];
    r[j] = fmaxf(z, 0.f);
  }
  *reinterpret_cast<float4*>(&hout[o]) = (float4){r[0], r[1], r[2], r[3]};
  u16x4 hb;
#pragma unroll
  for (int j = 0; j < 4; ++j) hb[j] = (unsigned short)f2bf(r[j]);
  *reinterpret_cast<u16x4*>(&hbf[o]) = hb;
}

// ---------------- layer-3 epilogue fused with FC classifier ----------------
__global__ __launch_bounds__(256) void k_postfc(
    const float* __restrict__ agg, const float* __restrict__ innorm,
    const float* __restrict__ b, const float* __restrict__ bnsum,
    const float* __restrict__ bnsq, const float* __restrict__ gamma,
    const float* __restrict__ beta, float inv_n,
    const float* __restrict__ hres, const float* __restrict__ fcW,
    const float* __restrict__ fcb, float* __restrict__ out, int n)
{
  __shared__ short hb[64 * 72];
  __shared__ short WPF[1024];

  const int tid = threadIdx.x, wave = tid >> 6, lane = tid & 63;
  const int lrow = lane & 15, lgrp = lane >> 4;
  const int row0 = blockIdx.x * 64;

  pack_w_lds(fcW, WPF, 64, 16);

#pragma unroll
  for (int j = 0; j < 16; ++j){
    int idx = j * 256 + tid;
    int row = idx >> 6, f = idx & 63;
    int grow = row0 + row;
    float r = 0.f;
    if (grow < n){
      float mu  = bnsum[f] * inv_n;
      float var = bnsq[f] * inv_n - mu * mu;
      float sc  = gamma[f] * rsqrtf(var + EPS_BN);
      float sh  = beta[f] - mu * sc;
      float z = agg[(size_t)grow * 64 + f] * innorm[grow] + b[f];
      z = z * sc + sh + hres[(size_t)grow * 64 + f];
      r = fmaxf(z, 0.f);
    }
    hb[row * 72 + f] = f2bf(r);
  }
  __syncthreads();

  f32x4 acc = (f32x4){0.f,0.f,0.f,0.f};
#pragma unroll
  for (int kstep = 0; kstep < 2; ++kstep){
    bf16x8 a = *reinterpret_cast<const bf16x8*>(&hb[(wave*16 + lrow) * 72 + kstep*32 + lgrp*8]);
    acc = __builtin_amdgcn_mfma_f32_16x16x32_bf16(a, wfrag(WPF,1,kstep,0,lgrp,lrow), acc, 0,0,0);
  }
  float bv = fcb[lrow];
#pragma unroll
  for (int r = 0; r < 4; ++r){
    int orow = row0 + wave*16 + lgrp*4 + r;
    if (orow < n) out[(size_t)orow * 16 + lrow] = acc[r] + bv;
  }
}

extern "C" void kernel_launch(void* const* d_in, const int* in_sizes, int n_in,
                              void* d_out, int out_size, void* d_ws, size_t ws_size,
                              hipStream_t stream) {
  const float* features = (const float*)d_in[0];
  const int*   src      = (const int*)d_in[1];
  const int*   dst      = (const int*)d_in[2];
  const float* encW1 = (const float*)d_in[3];  const float* encb1 = (const float*)d_in[4];
  const float* encW2 = (const float*)d_in[5];  const float* encb2 = (const float*)d_in[6];
  const float* encW3 = (const float*)d_in[7];  const float* encb3 = (const float*)d_in[8];
  const float* attW1 = (const float*)d_in[9];  const float* attb1 = (const float*)d_in[10];
  const float* attW2 = (const float*)d_in[11]; const float* attb2 = (const float*)d_in[12];
  const float* W0    = (const float*)d_in[13]; const float* b0    = (const float*)d_in[14];
  const float* Wrest = (const float*)d_in[15]; const float* brest = (const float*)d_in[16];
  const float* gamma = (const float*)d_in[17]; const float* beta  = (const float*)d_in[18];
  const float* fcW   = (const float*)d_in[19]; const float* fcb   = (const float*)d_in[20];
  float* out = (float*)d_out;

  const int n = in_sizes[0] / 128;   // 100000
  const int E = in_sizes[1];         // 1600000

  float* ws      = (float*)d_ws;
  float* agg     = ws;
  unsigned short* h_bf = (unsigned short*)(ws + (size_t)n * 64);
  float* p1      = ws + (size_t)n * 96;
  float* p2      = p1 + (size_t)GS_BLOCKS * 64;
  float* hbuf    = ws + (size_t)n * 128;
  float* nbhw    = hbuf + (size_t)n * 64;
  float* outnorm = nbhw + (size_t)n * 64;
  int*   cnt     = (int*)(outnorm + n);
  float* innorm  = (float*)(cnt + n);
  float* invind  = innorm + n;
  float* bnsum   = invind + n;
  float* bnsq    = bnsum + 256;
  int* rowptr = (int*)(bnsq + 256);
  int* csr    = rowptr + n + 1;
  int* bsum   = csr + E;
  int* rank = (int*)nbhw;
  unsigned short* nb_bf = (unsigned short*)nbhw;
  unsigned short* hw_bf = (unsigned short*)(nbhw + (size_t)n * 32);

  const int nt = cdiv_i(n, 64);
  const int nb = cdiv_i(n, SCAN_B);
  const float inv_n = 1.f / (float)n;

  // ---- degrees, norms, CSR build ----
  hipMemsetAsync(outnorm, 0, 2 * (size_t)n * sizeof(float), stream);
  k_cnt2<<<cdiv_i(E, 1024), 256, 0, stream>>>(src, dst, outnorm, cnt, rank, E);
  k_scan_a<<<nb, SCAN_B, 0, stream>>>(cnt, bsum, outnorm, innorm, invind, n);
  k_scan_b<<<1, 512, 0, stream>>>(bsum, nb, rowptr + n, E);
  k_scan_c<<<nb, SCAN_B, 0, stream>>>(cnt, bsum, rowptr, n);
  k_fill2<<<cdiv_i(E, 1024), 256, 0, stream>>>(src, dst, rowptr, rank, csr, E);

  // ---- fused encoder + layer-0 conv ----
  k_enc<<<nt, 256, 0, stream>>>(features, encW1, encb1, encW2, encb2, encW3, encb3,
                                W0, outnorm, hw_bf, n);
  k_gather_stats<<<GS_BLOCKS, 256, 0, stream>>>(hw_bf, rowptr, csr, innorm, b0, agg, p1, p2, n);
  k_bnred<<<128, 256, 0, stream>>>(p1, p2, bnsum, bnsq);
  k_post<<<cdiv_i(n * 16, 256), 256, 0, stream>>>(agg, innorm, b0, bnsum, bnsq, gamma, beta, inv_n,
                                                  nullptr, hbuf, h_bf, n * 16);

  // ---- layers 1..3 ----
  for (int i = 1; i < 4; ++i){
    const float* Wi = Wrest + (size_t)(i - 1) * 64 * 64;
    const float* bi = brest + (size_t)(i - 1) * 64;
    k_gather_nb<<<cdiv_i(n, 4), 256, 0, stream>>>(h_bf, rowptr, csr, nb_bf, n);
    k_attconv<<<nt, 256, 0, stream>>>(hbuf, nb_bf, invind, outnorm,
                                      attW1, attb1, attW2, attb2, Wi, hw_bf, n);
    k_gather_stats<<<GS_BLOCKS, 256, 0, stream>>>(hw_bf, rowptr, csr, innorm, bi, agg, p1, p2, n);
    k_bnred<<<128, 256, 0, stream>>>(p1, p2, bnsum + i * 64, bnsq + i * 64);
    if (i < 3){
      k_post<<<cdiv_i(n * 16, 256), 256, 0, stream>>>(agg, innorm, bi, bnsum + i * 64, bnsq + i * 64,
                                                      gamma + i * 64, beta + i * 64, inv_n,
                                                      hbuf, hbuf, h_bf, n * 16);
    } else {
      k_postfc<<<nt, 256, 0, stream>>>(agg, innorm, bi, bnsum + i * 64, bnsq + i * 64,
                                       gamma + i * 64, beta + i * 64, inv_n,
                                       hbuf, fcW, fcb, out, n);
    }
  }
}